// Round 4
// baseline (318.485 us; speedup 1.0000x reference)
//
#include <hip/hip_runtime.h>

#define NE 8
#define TA 8192
#define MAXT 40                 // max 256-row tiles: worst case 32+7+1
#define MAXPAD (MAXT*256)       // 10240

typedef __attribute__((ext_vector_type(4)))  float f32x4;
typedef __attribute__((ext_vector_type(16))) float f32x16;
typedef __attribute__((ext_vector_type(8)))  short s16x8;

// ws int-area layout (int indices)
#define WS_CNT  0    // [8]
#define WS_CUR  8    // [8]
#define WS_META 16   // [2] {ntiles, total_padded}
#define WS_TEXP 18   // [<=40] tile -> expert
#define WS_PERM 256  // [MAXPAD] sorted row -> ta index (or -1 = pad)

#define WAITVM0() asm volatile("s_waitcnt vmcnt(0)" ::: "memory")
#define BAR()     asm volatile("s_barrier" ::: "memory")

__device__ __forceinline__ unsigned short f2bf(float f) {
  unsigned u = __builtin_bit_cast(unsigned, f);
  u += 0x7FFFu + ((u >> 16) & 1u);   // RNE (inputs finite)
  return (unsigned short)(u >> 16);
}

__device__ __forceinline__ void glds16(const unsigned short* g, unsigned short* l) {
  __builtin_amdgcn_global_load_lds(
      (const __attribute__((address_space(1))) unsigned int*)g,
      (__attribute__((address_space(3))) unsigned int*)l, 16, 0, 0);
}

// stage a 256x64 tile (A or B half) as 4 x 8KB issues; source pre-swizzled
template <int STRIDE>
__device__ __forceinline__ void stage_t(const unsigned short* g, unsigned short* Lb,
                                        int k0, int tid) {
#pragma unroll
  for (int i = 0; i < 4; ++i)
    glds16(g + (size_t)i * 64 * STRIDE + k0, Lb + i * 4096 + tid * 8);
}

// ---------------- routing (pad each expert to 256) ----------------
__global__ void k_count(const int* __restrict__ idx, int* __restrict__ ws) {
  int i = blockIdx.x * 256 + threadIdx.x;
  if (i < TA) atomicAdd(&ws[WS_CNT + idx[i]], 1);
}

__global__ void k_scan(int* __restrict__ ws) {
  if (threadIdx.x == 0) {
    int off = 0, ti = 0;
    for (int e = 0; e < NE; ++e) {
      ws[WS_CUR + e] = off;
      int c = ws[WS_CNT + e];
      int nt = (c + 255) / 256;
      for (int k = 0; k < nt; ++k) ws[WS_TEXP + ti++] = e;
      off += nt * 256;
    }
    ws[WS_META] = ti;
    ws[WS_META + 1] = off;
  }
}

__global__ void k_place(const int* __restrict__ idx, int* __restrict__ ws) {
  int i = blockIdx.x * 256 + threadIdx.x;
  if (i < TA) {
    int e = idx[i];
    int pos = atomicAdd(&ws[WS_CUR + e], 1);
    ws[WS_PERM + pos] = i;
  }
}

// ---------------- f32 -> bf16 plain convert (w_down) ----------------
__global__ void k_cvt(const float* __restrict__ s, unsigned short* __restrict__ d) {
  int i = (blockIdx.x * 256 + threadIdx.x) * 8;
  f32x4 a = *(const f32x4*)(s + i);
  f32x4 b = *(const f32x4*)(s + i + 4);
  s16x8 o;
  o[0] = (short)f2bf(a[0]); o[1] = (short)f2bf(a[1]);
  o[2] = (short)f2bf(a[2]); o[3] = (short)f2bf(a[3]);
  o[4] = (short)f2bf(b[0]); o[5] = (short)f2bf(b[1]);
  o[6] = (short)f2bf(b[2]); o[7] = (short)f2bf(b[3]);
  *(s16x8*)(d + i) = o;
}

// ---------------- gate/up convert with 32-row interleave ----------------
// dest row (per expert, 4096 rows): (h>>5)*64 + off + (h&31); off=0 gate, 32 up
__global__ void k_cvt_gu(const float* __restrict__ s, unsigned short* __restrict__ d, int off) {
  int t = blockIdx.x * 256 + threadIdx.x;
  int i = t * 8;
  int dd = i & 1023;
  int h = (i >> 10) & 2047;
  int e = i >> 21;
  int drow = (e << 12) + ((h >> 5) << 6) + off + (h & 31);
  f32x4 a = *(const f32x4*)(s + i);
  f32x4 b = *(const f32x4*)(s + i + 4);
  s16x8 o;
  o[0] = (short)f2bf(a[0]); o[1] = (short)f2bf(a[1]);
  o[2] = (short)f2bf(a[2]); o[3] = (short)f2bf(a[3]);
  o[4] = (short)f2bf(b[0]); o[5] = (short)f2bf(b[1]);
  o[6] = (short)f2bf(b[2]); o[7] = (short)f2bf(b[3]);
  *(s16x8*)(d + (size_t)drow * 1024 + dd) = o;
}

// ---------------- gather x rows (permuted, bf16, zero pads) ----------------
__global__ void k_gather(const float* __restrict__ x, const int* __restrict__ ws,
                         unsigned short* __restrict__ xb) {
  int tid = blockIdx.x * 256 + threadIdx.x;
  int r = tid >> 7;
  int c = (tid & 127) << 3;
  int ta = ws[WS_PERM + r];
  s16x8 o = {0,0,0,0,0,0,0,0};
  if (ta >= 0) {
    const float* xp = x + (size_t)(ta >> 1) * 1024 + c;
    f32x4 a = *(const f32x4*)xp;
    f32x4 b = *(const f32x4*)(xp + 4);
    o[0] = (short)f2bf(a[0]); o[1] = (short)f2bf(a[1]);
    o[2] = (short)f2bf(a[2]); o[3] = (short)f2bf(a[3]);
    o[4] = (short)f2bf(b[0]); o[5] = (short)f2bf(b[1]);
    o[6] = (short)f2bf(b[2]); o[7] = (short)f2bf(b[3]);
  }
  *(s16x8*)(xb + (size_t)r * 1024 + c) = o;
}

// ---------------- GEMM1: 256x256 tile, 32x32x16 MFMA, fused gate/up ----------------
// B = wgu interleaved (per 32-h group: 32 gate rows, 32 up rows). nt covers 128 h.
__global__ __launch_bounds__(512) void k_gemm1(
    const unsigned short* __restrict__ xb, const unsigned short* __restrict__ wgu,
    unsigned short* __restrict__ hb, const int* __restrict__ ws) {
  int mt = blockIdx.y;
  if (mt >= ws[WS_META]) return;
  int e = ws[WS_TEXP + mt];
  int nt = blockIdx.x;   // 0..15

  __shared__ unsigned short L[2][32768];   // [A 16384 | B 16384] elems; 128KB

  int tid = threadIdx.x;
  int lane = tid & 63, wid = tid >> 6;
  int wm = wid >> 2, wn = wid & 3;         // 2M x 4N
  int lr = tid >> 3;                       // staging row 0..63
  int cs = (tid & 7) ^ (lr & 7);           // pre-swizzled source chunk

  const unsigned short* gA = xb  + (size_t)(mt * 256 + lr) * 1024 + cs * 8;
  const unsigned short* gB = wgu + (size_t)(e * 4096 + nt * 256 + lr) * 1024 + cs * 8;

  f32x16 accg[4] = {};
  f32x16 accu[4] = {};

  int r31 = lane & 31, kg = lane >> 5, x7 = r31 & 7;
  int arow = wm * 128 + r31;               // + mi*32
  int brow = wn * 64 + r31;                // + ni*32

  stage_t<1024>(gA, &L[0][0], 0, tid);
  stage_t<1024>(gB, &L[0][16384], 0, tid);

#pragma unroll 2
  for (int kt = 0; kt < 16; ++kt) {
    int cur = kt & 1;
    WAITVM0();                 // my 8 loads for tile kt landed (issued 1 tile ago)
    BAR();                     // whole tile resident; prev-buf reads all done
    if (kt + 1 < 16) {
      stage_t<1024>(gA, &L[cur ^ 1][0],     (kt + 1) * 64, tid);
      stage_t<1024>(gB, &L[cur ^ 1][16384], (kt + 1) * 64, tid);
    }
    const unsigned short* Ab = &L[cur][0];
    const unsigned short* Bb = &L[cur][16384];
#pragma unroll
    for (int ks = 0; ks < 4; ++ks) {
      int kc = ks * 2 + kg;
      int slot = (kc ^ x7) * 8;
      s16x8 a[4], bg, bu;
#pragma unroll
      for (int mi = 0; mi < 4; ++mi)
        a[mi] = *(const s16x8*)&Ab[(arow + mi * 32) * 64 + slot];
      bg = *(const s16x8*)&Bb[brow * 64 + slot];
      bu = *(const s16x8*)&Bb[(brow + 32) * 64 + slot];
      __builtin_amdgcn_s_setprio(1);
#pragma unroll
      for (int mi = 0; mi < 4; ++mi) {
        accg[mi] = __builtin_amdgcn_mfma_f32_32x32x16_bf16(a[mi], bg, accg[mi], 0, 0, 0);
        accu[mi] = __builtin_amdgcn_mfma_f32_32x32x16_bf16(a[mi], bu, accu[mi], 0, 0, 0);
      }
      __builtin_amdgcn_s_setprio(0);
    }
  }

  // epilogue: C layout 32x32: col=lane&31, row=(r&3)+8*(r>>2)+4*(lane>>5)
  int hrow0 = mt * 256 + wm * 128;
  int hcol  = nt * 128 + wn * 32 + r31;
#pragma unroll
  for (int mi = 0; mi < 4; ++mi)
#pragma unroll
    for (int r = 0; r < 16; ++r) {
      int crow = (r & 3) + 8 * (r >> 2) + 4 * kg;
      float g = accg[mi][r];
      float u = accu[mi][r];
      float h = (g / (1.f + __expf(-g))) * u;
      hb[(size_t)(hrow0 + mi * 32 + crow) * 2048 + hcol] = f2bf(h);
    }
}

// ---------------- GEMM2: 256x256 tile, 32x32x16 MFMA, K=2048, scatter ----------------
__global__ __launch_bounds__(512) void k_gemm2(
    const unsigned short* __restrict__ hb, const unsigned short* __restrict__ wdb,
    float* __restrict__ out, const int* __restrict__ ws) {
  int mt = blockIdx.y;
  if (mt >= ws[WS_META]) return;
  int e = ws[WS_TEXP + mt];
  int nt = blockIdx.x;   // 0..3

  __shared__ unsigned short L[2][32768];

  int tid = threadIdx.x;
  int lane = tid & 63, wid = tid >> 6;
  int wm = wid >> 2, wn = wid & 3;
  int lr = tid >> 3;
  int cs = (tid & 7) ^ (lr & 7);

  const unsigned short* gA = hb  + (size_t)(mt * 256 + lr) * 2048 + cs * 8;
  const unsigned short* gB = wdb + (size_t)(e * 1024 + nt * 256 + lr) * 2048 + cs * 8;

  f32x16 acc0[4] = {};
  f32x16 acc1[4] = {};

  int r31 = lane & 31, kg = lane >> 5, x7 = r31 & 7;
  int arow = wm * 128 + r31;
  int brow = wn * 64 + r31;

  stage_t<2048>(gA, &L[0][0], 0, tid);
  stage_t<2048>(gB, &L[0][16384], 0, tid);

#pragma unroll 2
  for (int kt = 0; kt < 32; ++kt) {
    int cur = kt & 1;
    WAITVM0();
    BAR();
    if (kt + 1 < 32) {
      stage_t<2048>(gA, &L[cur ^ 1][0],     (kt + 1) * 64, tid);
      stage_t<2048>(gB, &L[cur ^ 1][16384], (kt + 1) * 64, tid);
    }
    const unsigned short* Ab = &L[cur][0];
    const unsigned short* Bb = &L[cur][16384];
#pragma unroll
    for (int ks = 0; ks < 4; ++ks) {
      int kc = ks * 2 + kg;
      int slot = (kc ^ x7) * 8;
      s16x8 a[4], b0, b1;
#pragma unroll
      for (int mi = 0; mi < 4; ++mi)
        a[mi] = *(const s16x8*)&Ab[(arow + mi * 32) * 64 + slot];
      b0 = *(const s16x8*)&Bb[brow * 64 + slot];
      b1 = *(const s16x8*)&Bb[(brow + 32) * 64 + slot];
      __builtin_amdgcn_s_setprio(1);
#pragma unroll
      for (int mi = 0; mi < 4; ++mi) {
        acc0[mi] = __builtin_amdgcn_mfma_f32_32x32x16_bf16(a[mi], b0, acc0[mi], 0, 0, 0);
        acc1[mi] = __builtin_amdgcn_mfma_f32_32x32x16_bf16(a[mi], b1, acc1[mi], 0, 0, 0);
      }
      __builtin_amdgcn_s_setprio(0);
    }
  }

  int prow0 = mt * 256 + wm * 128;
  int dcol  = nt * 256 + wn * 64 + r31;
#pragma unroll
  for (int mi = 0; mi < 4; ++mi)
#pragma unroll
    for (int r = 0; r < 16; ++r) {
      int crow = (r & 3) + 8 * (r >> 2) + 4 * kg;
      int ta = ws[WS_PERM + prow0 + mi * 32 + crow];
      if (ta >= 0) {
        out[(size_t)ta * 1024 + dcol]      = acc0[mi][r];
        out[(size_t)ta * 1024 + dcol + 32] = acc1[mi][r];
      }
    }
}

extern "C" void kernel_launch(void* const* d_in, const int* in_sizes, int n_in,
                              void* d_out, int out_size, void* d_ws, size_t ws_size,
                              hipStream_t stream) {
  const float* x   = (const float*)d_in[0];
  const int*   idx = (const int*)d_in[1];
  const float* wg  = (const float*)d_in[2];
  const float* wu  = (const float*)d_in[3];
  const float* wd  = (const float*)d_in[4];
  float* out = (float*)d_out;

  int*  wsi = (int*)d_ws;
  char* wsb = (char*)d_ws;
  // xb and wdb OVERLAY (xb dead after gemm1; cvt_wd runs after gemm1)
  const size_t OFF_XB  = 65536;                         // 20.97 MB (xb)
  const size_t OFF_WDB = 65536;                         // 33.55 MB (wdb, later)
  const size_t OFF_WGU = 65536 + (size_t)NE * 1024 * 2048 * 2;   // after wdb span
  const size_t OFF_HB  = OFF_WGU + (size_t)NE * 4096 * 1024 * 2; // 67.1 MB wgu
  unsigned short* xbuf = (unsigned short*)(wsb + OFF_XB);
  unsigned short* wdb  = (unsigned short*)(wsb + OFF_WDB);
  unsigned short* wgu  = (unsigned short*)(wsb + OFF_WGU);
  unsigned short* hb   = (unsigned short*)(wsb + OFF_HB);

  hipMemsetAsync(wsi, 0, 96 * sizeof(int), stream);
  hipMemsetAsync(wsi + WS_PERM, 0xFF, MAXPAD * sizeof(int), stream);

  k_count<<<TA / 256, 256, 0, stream>>>(idx, wsi);
  k_scan<<<1, 64, 0, stream>>>(wsi);
  k_place<<<TA / 256, 256, 0, stream>>>(idx, wsi);

  k_cvt_gu<<<(NE * 2048 * 1024) / (256 * 8), 256, 0, stream>>>(wg, wgu, 0);
  k_cvt_gu<<<(NE * 2048 * 1024) / (256 * 8), 256, 0, stream>>>(wu, wgu, 32);
  k_gather<<<(MAXPAD * 128) / 256, 256, 0, stream>>>(x, wsi, xbuf);

  k_gemm1<<<dim3(16, MAXT), 512, 0, stream>>>(xbuf, wgu, hb, wsi);

  k_cvt<<<(NE * 1024 * 2048) / (256 * 8), 256, 0, stream>>>(wd, wdb);   // after gemm1 (overlay)

  k_gemm2<<<dim3(4, MAXT), 512, 0, stream>>>(hb, wdb, out, wsi);
}

// Round 5
// 317.100 us; speedup vs baseline: 1.0044x; 1.0044x over previous
//
#include <hip/hip_runtime.h>

#define NE 8
#define TA 8192
#define MAXT 40                 // max 256-row tiles: worst case 32+7+1
#define MAXPAD (MAXT*256)       // 10240

typedef __attribute__((ext_vector_type(4)))  float f32x4;
typedef __attribute__((ext_vector_type(16))) float f32x16;
typedef __attribute__((ext_vector_type(8)))  short s16x8;

// ws int-area layout (int indices)
#define WS_CNT  0    // [8]
#define WS_CUR  8    // [8]
#define WS_META 16   // [2] {ntiles, total_padded}
#define WS_TEXP 18   // [<=40] tile -> expert
#define WS_PERM 256  // [MAXPAD] sorted row -> ta index (or -1 = pad)

#define WAITVM0() asm volatile("s_waitcnt vmcnt(0)" ::: "memory")
#define BAR()     asm volatile("s_barrier" ::: "memory")

__device__ __forceinline__ unsigned short f2bf(float f) {
  unsigned u = __builtin_bit_cast(unsigned, f);
  u += 0x7FFFu + ((u >> 16) & 1u);   // RNE (inputs finite)
  return (unsigned short)(u >> 16);
}

__device__ __forceinline__ void glds16(const unsigned short* g, unsigned short* l) {
  __builtin_amdgcn_global_load_lds(
      (const __attribute__((address_space(1))) unsigned int*)g,
      (__attribute__((address_space(3))) unsigned int*)l, 16, 0, 0);
}

// stage a 256x64 tile (A or B half) as 4 x 8KB issues; source pre-swizzled
template <int STRIDE>
__device__ __forceinline__ void stage_t(const unsigned short* g, unsigned short* Lb,
                                        int k0, int tid) {
#pragma unroll
  for (int i = 0; i < 4; ++i)
    glds16(g + (size_t)i * 64 * STRIDE + k0, Lb + i * 4096 + tid * 8);
}

// ---------------- routing (pad each expert to 256) ----------------
__global__ void k_count(const int* __restrict__ idx, int* __restrict__ ws) {
  int i = blockIdx.x * 256 + threadIdx.x;
  if (i < TA) atomicAdd(&ws[WS_CNT + idx[i]], 1);
}

__global__ void k_scan(int* __restrict__ ws) {
  if (threadIdx.x == 0) {
    int off = 0, ti = 0;
    for (int e = 0; e < NE; ++e) {
      ws[WS_CUR + e] = off;
      int c = ws[WS_CNT + e];
      int nt = (c + 255) / 256;
      for (int k = 0; k < nt; ++k) ws[WS_TEXP + ti++] = e;
      off += nt * 256;
    }
    ws[WS_META] = ti;
    ws[WS_META + 1] = off;
  }
}

__global__ void k_place(const int* __restrict__ idx, int* __restrict__ ws) {
  int i = blockIdx.x * 256 + threadIdx.x;
  if (i < TA) {
    int e = idx[i];
    int pos = atomicAdd(&ws[WS_CUR + e], 1);
    ws[WS_PERM + pos] = i;
  }
}

// ---------------- f32 -> bf16 plain convert (w_down) ----------------
__global__ void k_cvt(const float* __restrict__ s, unsigned short* __restrict__ d) {
  int i = (blockIdx.x * 256 + threadIdx.x) * 8;
  f32x4 a = *(const f32x4*)(s + i);
  f32x4 b = *(const f32x4*)(s + i + 4);
  s16x8 o;
  o[0] = (short)f2bf(a[0]); o[1] = (short)f2bf(a[1]);
  o[2] = (short)f2bf(a[2]); o[3] = (short)f2bf(a[3]);
  o[4] = (short)f2bf(b[0]); o[5] = (short)f2bf(b[1]);
  o[6] = (short)f2bf(b[2]); o[7] = (short)f2bf(b[3]);
  *(s16x8*)(d + i) = o;
}

// ---------------- gate/up convert with 32-row interleave ----------------
// dest row (per expert, 4096 rows): (h>>5)*64 + off + (h&31); off=0 gate, 32 up
__global__ void k_cvt_gu(const float* __restrict__ s, unsigned short* __restrict__ d, int off) {
  int t = blockIdx.x * 256 + threadIdx.x;
  int i = t * 8;
  int dd = i & 1023;
  int h = (i >> 10) & 2047;
  int e = i >> 21;
  int drow = (e << 12) + ((h >> 5) << 6) + off + (h & 31);
  f32x4 a = *(const f32x4*)(s + i);
  f32x4 b = *(const f32x4*)(s + i + 4);
  s16x8 o;
  o[0] = (short)f2bf(a[0]); o[1] = (short)f2bf(a[1]);
  o[2] = (short)f2bf(a[2]); o[3] = (short)f2bf(a[3]);
  o[4] = (short)f2bf(b[0]); o[5] = (short)f2bf(b[1]);
  o[6] = (short)f2bf(b[2]); o[7] = (short)f2bf(b[3]);
  *(s16x8*)(d + (size_t)drow * 1024 + dd) = o;
}

// ---------------- gather x rows (permuted, bf16, zero pads) ----------------
__global__ void k_gather(const float* __restrict__ x, const int* __restrict__ ws,
                         unsigned short* __restrict__ xb) {
  int tid = blockIdx.x * 256 + threadIdx.x;
  int r = tid >> 7;
  int c = (tid & 127) << 3;
  int ta = ws[WS_PERM + r];
  s16x8 o = {0,0,0,0,0,0,0,0};
  if (ta >= 0) {
    const float* xp = x + (size_t)(ta >> 1) * 1024 + c;
    f32x4 a = *(const f32x4*)xp;
    f32x4 b = *(const f32x4*)(xp + 4);
    o[0] = (short)f2bf(a[0]); o[1] = (short)f2bf(a[1]);
    o[2] = (short)f2bf(a[2]); o[3] = (short)f2bf(a[3]);
    o[4] = (short)f2bf(b[0]); o[5] = (short)f2bf(b[1]);
    o[6] = (short)f2bf(b[2]); o[7] = (short)f2bf(b[3]);
  }
  *(s16x8*)(xb + (size_t)r * 1024 + c) = o;
}

// ---------------- GEMM1: 256x256 tile, 32x32x16 MFMA, fused gate/up ----------------
// B = wgu interleaved (per 32-h group: 32 gate rows, 32 up rows). nt covers 128 h.
__global__ __launch_bounds__(512) void k_gemm1(
    const unsigned short* __restrict__ xb, const unsigned short* __restrict__ wgu,
    unsigned short* __restrict__ hb, const int* __restrict__ ws) {
  int mt = blockIdx.y;
  if (mt >= ws[WS_META]) return;
  int e = ws[WS_TEXP + mt];
  int nt = blockIdx.x;   // 0..15

  __shared__ unsigned short L[2][32768];   // [A 16384 | B 16384] elems; 128KB

  int tid = threadIdx.x;
  int lane = tid & 63, wid = tid >> 6;
  int wm = wid >> 2, wn = wid & 3;         // 2M x 4N
  int lr = tid >> 3;                       // staging row 0..63
  int cs = (tid & 7) ^ (lr & 7);           // pre-swizzled source chunk

  const unsigned short* gA = xb  + (size_t)(mt * 256 + lr) * 1024 + cs * 8;
  const unsigned short* gB = wgu + (size_t)(e * 4096 + nt * 256 + lr) * 1024 + cs * 8;

  f32x16 accg[4] = {};
  f32x16 accu[4] = {};

  int r31 = lane & 31, kg = lane >> 5, x7 = r31 & 7;
  int arow = wm * 128 + r31;               // + mi*32
  int brow = wn * 64 + r31;                // + ni*32

  stage_t<1024>(gA, &L[0][0], 0, tid);
  stage_t<1024>(gB, &L[0][16384], 0, tid);

#pragma unroll 2
  for (int kt = 0; kt < 16; ++kt) {
    int cur = kt & 1;
    WAITVM0();                 // my 8 loads for tile kt landed (issued 1 tile ago)
    BAR();                     // whole tile resident; prev-buf reads all done
    if (kt + 1 < 16) {
      stage_t<1024>(gA, &L[cur ^ 1][0],     (kt + 1) * 64, tid);
      stage_t<1024>(gB, &L[cur ^ 1][16384], (kt + 1) * 64, tid);
    }
    const unsigned short* Ab = &L[cur][0];
    const unsigned short* Bb = &L[cur][16384];
#pragma unroll
    for (int ks = 0; ks < 4; ++ks) {
      int kc = ks * 2 + kg;
      int slot = (kc ^ x7) * 8;
      s16x8 a[4], bg, bu;
#pragma unroll
      for (int mi = 0; mi < 4; ++mi)
        a[mi] = *(const s16x8*)&Ab[(arow + mi * 32) * 64 + slot];
      bg = *(const s16x8*)&Bb[brow * 64 + slot];
      bu = *(const s16x8*)&Bb[(brow + 32) * 64 + slot];
      __builtin_amdgcn_s_setprio(1);
#pragma unroll
      for (int mi = 0; mi < 4; ++mi) {
        accg[mi] = __builtin_amdgcn_mfma_f32_32x32x16_bf16(a[mi], bg, accg[mi], 0, 0, 0);
        accu[mi] = __builtin_amdgcn_mfma_f32_32x32x16_bf16(a[mi], bu, accu[mi], 0, 0, 0);
      }
      __builtin_amdgcn_s_setprio(0);
    }
  }

  // epilogue: C layout 32x32: col=lane&31, row=(r&3)+8*(r>>2)+4*(lane>>5)
  int hrow0 = mt * 256 + wm * 128;
  int hcol  = nt * 128 + wn * 32 + r31;
#pragma unroll
  for (int mi = 0; mi < 4; ++mi)
#pragma unroll
    for (int r = 0; r < 16; ++r) {
      int crow = (r & 3) + 8 * (r >> 2) + 4 * kg;
      float g = accg[mi][r];
      float u = accu[mi][r];
      float h = (g / (1.f + __expf(-g))) * u;
      hb[(size_t)(hrow0 + mi * 32 + crow) * 2048 + hcol] = f2bf(h);
    }
}

// ---------------- GEMM2: 256x256 tile, 32x32x16 MFMA, K=2048, scatter ----------------
__global__ __launch_bounds__(512) void k_gemm2(
    const unsigned short* __restrict__ hb, const unsigned short* __restrict__ wdb,
    float* __restrict__ out, const int* __restrict__ ws) {
  int mt = blockIdx.y;
  if (mt >= ws[WS_META]) return;
  int e = ws[WS_TEXP + mt];
  int nt = blockIdx.x;   // 0..3

  __shared__ unsigned short L[2][32768];

  int tid = threadIdx.x;
  int lane = tid & 63, wid = tid >> 6;
  int wm = wid >> 2, wn = wid & 3;
  int lr = tid >> 3;
  int cs = (tid & 7) ^ (lr & 7);

  const unsigned short* gA = hb  + (size_t)(mt * 256 + lr) * 2048 + cs * 8;
  const unsigned short* gB = wdb + (size_t)(e * 1024 + nt * 256 + lr) * 2048 + cs * 8;

  f32x16 acc0[4] = {};
  f32x16 acc1[4] = {};

  int r31 = lane & 31, kg = lane >> 5, x7 = r31 & 7;
  int arow = wm * 128 + r31;
  int brow = wn * 64 + r31;

  stage_t<2048>(gA, &L[0][0], 0, tid);
  stage_t<2048>(gB, &L[0][16384], 0, tid);

#pragma unroll 2
  for (int kt = 0; kt < 32; ++kt) {
    int cur = kt & 1;
    WAITVM0();
    BAR();
    if (kt + 1 < 32) {
      stage_t<2048>(gA, &L[cur ^ 1][0],     (kt + 1) * 64, tid);
      stage_t<2048>(gB, &L[cur ^ 1][16384], (kt + 1) * 64, tid);
    }
    const unsigned short* Ab = &L[cur][0];
    const unsigned short* Bb = &L[cur][16384];
#pragma unroll
    for (int ks = 0; ks < 4; ++ks) {
      int kc = ks * 2 + kg;
      int slot = (kc ^ x7) * 8;
      s16x8 a[4], b0, b1;
#pragma unroll
      for (int mi = 0; mi < 4; ++mi)
        a[mi] = *(const s16x8*)&Ab[(arow + mi * 32) * 64 + slot];
      b0 = *(const s16x8*)&Bb[brow * 64 + slot];
      b1 = *(const s16x8*)&Bb[(brow + 32) * 64 + slot];
      __builtin_amdgcn_s_setprio(1);
#pragma unroll
      for (int mi = 0; mi < 4; ++mi) {
        acc0[mi] = __builtin_amdgcn_mfma_f32_32x32x16_bf16(a[mi], b0, acc0[mi], 0, 0, 0);
        acc1[mi] = __builtin_amdgcn_mfma_f32_32x32x16_bf16(a[mi], b1, acc1[mi], 0, 0, 0);
      }
      __builtin_amdgcn_s_setprio(0);
    }
  }

  int prow0 = mt * 256 + wm * 128;
  int dcol  = nt * 256 + wn * 64 + r31;
#pragma unroll
  for (int mi = 0; mi < 4; ++mi)
#pragma unroll
    for (int r = 0; r < 16; ++r) {
      int crow = (r & 3) + 8 * (r >> 2) + 4 * kg;
      int ta = ws[WS_PERM + prow0 + mi * 32 + crow];
      if (ta >= 0) {
        out[(size_t)ta * 1024 + dcol]      = acc0[mi][r];
        out[(size_t)ta * 1024 + dcol + 32] = acc1[mi][r];
      }
    }
}

extern "C" void kernel_launch(void* const* d_in, const int* in_sizes, int n_in,
                              void* d_out, int out_size, void* d_ws, size_t ws_size,
                              hipStream_t stream) {
  const float* x   = (const float*)d_in[0];
  const int*   idx = (const int*)d_in[1];
  const float* wg  = (const float*)d_in[2];
  const float* wu  = (const float*)d_in[3];
  const float* wd  = (const float*)d_in[4];
  float* out = (float*)d_out;

  int*  wsi = (int*)d_ws;
  char* wsb = (char*)d_ws;
  // xb and wdb OVERLAY (xb dead after gemm1; cvt_wd runs after gemm1)
  const size_t OFF_XB  = 65536;                         // 20.97 MB (xb)
  const size_t OFF_WDB = 65536;                         // 33.55 MB (wdb, later)
  const size_t OFF_WGU = 65536 + (size_t)NE * 1024 * 2048 * 2;   // after wdb span
  const size_t OFF_HB  = OFF_WGU + (size_t)NE * 4096 * 1024 * 2; // 67.1 MB wgu
  unsigned short* xbuf = (unsigned short*)(wsb + OFF_XB);
  unsigned short* wdb  = (unsigned short*)(wsb + OFF_WDB);
  unsigned short* wgu  = (unsigned short*)(wsb + OFF_WGU);
  unsigned short* hb   = (unsigned short*)(wsb + OFF_HB);

  hipMemsetAsync(wsi, 0, 96 * sizeof(int), stream);
  hipMemsetAsync(wsi + WS_PERM, 0xFF, MAXPAD * sizeof(int), stream);

  k_count<<<TA / 256, 256, 0, stream>>>(idx, wsi);
  k_scan<<<1, 64, 0, stream>>>(wsi);
  k_place<<<TA / 256, 256, 0, stream>>>(idx, wsi);

  k_cvt_gu<<<(NE * 2048 * 1024) / (256 * 8), 256, 0, stream>>>(wg, wgu, 0);
  k_cvt_gu<<<(NE * 2048 * 1024) / (256 * 8), 256, 0, stream>>>(wu, wgu, 32);
  k_gather<<<(MAXPAD * 128) / 256, 256, 0, stream>>>(x, wsi, xbuf);

  k_gemm1<<<dim3(16, MAXT), 512, 0, stream>>>(xbuf, wgu, hb, wsi);

  k_cvt<<<(NE * 1024 * 2048) / (256 * 8), 256, 0, stream>>>(wd, wdb);   // after gemm1 (overlay)

  k_gemm2<<<dim3(4, MAXT), 512, 0, stream>>>(hb, wdb, out, wsi);
}